// Round 1
// baseline (2199.386 us; speedup 1.0000x reference)
//
#include <hip/hip_runtime.h>
#include <math.h>

#define NQ 8
#define K 1024
#define D 64
#define CHUNK 128            // codes per LDS chunk
#define NCHUNK (K / CHUNK)   // 8
#define TPB 256              // threads per block = tokens per block
#define PAD_F4 17            // float4 stride per code row (68 floats) — pad for c_sq pass

__global__ __launch_bounds__(TPB) void rvq_fp32_kernel(
    const float* __restrict__ x,
    const float* __restrict__ cb,    // [NQ][K][D]
    float* __restrict__ out,
    int n_tokens)
{
    __shared__ float4 lds[CHUNK * PAD_F4];   // 34816 B
    __shared__ float lds_csq[CHUNK];

    const int tid = threadIdx.x;
    const int token = blockIdx.x * TPB + tid;
    const int token_ld = token < n_tokens ? token : (n_tokens - 1);

    // residual = x[token]
    float4 r[16];
    {
        const float4* xp = (const float4*)(x + (size_t)token_ld * D);
        #pragma unroll
        for (int j = 0; j < 16; ++j) r[j] = xp[j];
    }

    for (int q = 0; q < NQ; ++q) {
        float best = 3.4e38f;
        int bidx = 0;

        for (int ch = 0; ch < NCHUNK; ++ch) {
            const int c0 = ch * CHUNK;

            __syncthreads();   // previous chunk fully consumed before overwrite

            // ---- stage chunk: CHUNK*D floats = 2048 float4, coalesced ----
            {
                const float4* src = (const float4*)(cb + ((size_t)q * K + c0) * D);
                #pragma unroll
                for (int t = 0; t < (CHUNK * D / 4) / TPB; ++t) {
                    int g = tid + t * TPB;            // 0..2047
                    int code = g >> 4;                 // /16 float4 per code
                    int j = g & 15;
                    lds[code * PAD_F4 + j] = src[g];
                }
            }
            __syncthreads();

            // ---- c_sq for this chunk (threads 0..CHUNK-1, one code each) ----
            if (tid < CHUNK) {
                const float4* cp = &lds[tid * PAD_F4];
                float s0 = 0.f, s1 = 0.f, s2 = 0.f, s3 = 0.f;
                #pragma unroll
                for (int j = 0; j < 16; ++j) {
                    float4 c = cp[j];
                    s0 += c.x * c.x; s1 += c.y * c.y;
                    s2 += c.z * c.z; s3 += c.w * c.w;
                }
                lds_csq[tid] = (s0 + s1) + (s2 + s3);
            }
            __syncthreads();

            // ---- score CHUNK codes, 2 at a time (8 independent FMA chains) ----
            for (int k = 0; k < CHUNK; k += 2) {
                const float4* c0p = &lds[k * PAD_F4];
                const float4* c1p = &lds[(k + 1) * PAD_F4];
                float ax0 = 0.f, ay0 = 0.f, az0 = 0.f, aw0 = 0.f;
                float ax1 = 0.f, ay1 = 0.f, az1 = 0.f, aw1 = 0.f;
                #pragma unroll
                for (int j = 0; j < 16; ++j) {
                    float4 ca = c0p[j];
                    float4 cbv = c1p[j];
                    float4 rv = r[j];
                    ax0 += rv.x * ca.x;  ay0 += rv.y * ca.y;
                    az0 += rv.z * ca.z;  aw0 += rv.w * ca.w;
                    ax1 += rv.x * cbv.x; ay1 += rv.y * cbv.y;
                    az1 += rv.z * cbv.z; aw1 += rv.w * cbv.w;
                }
                float dot0 = (ax0 + ay0) + (az0 + aw0);
                float dot1 = (ax1 + ay1) + (az1 + aw1);
                float dist0 = lds_csq[k]     - 2.0f * dot0;
                float dist1 = lds_csq[k + 1] - 2.0f * dot1;
                if (dist0 < best) { best = dist0; bidx = c0 + k; }
                if (dist1 < best) { best = dist1; bidx = c0 + k + 1; }
            }
        }

        // ---- residual update: gather chosen code from global (L2-hot) ----
        {
            const float4* qp = (const float4*)(cb + ((size_t)q * K + bidx) * D);
            #pragma unroll
            for (int j = 0; j < 16; ++j) {
                float4 c = qp[j];
                r[j].x -= c.x; r[j].y -= c.y; r[j].z -= c.z; r[j].w -= c.w;
            }
        }
    }

    // ---- epilogue: out = x - residual_final ----
    if (token < n_tokens) {
        const float4* xp = (const float4*)(x + (size_t)token * D);
        float4* op = (float4*)(out + (size_t)token * D);
        #pragma unroll
        for (int j = 0; j < 16; ++j) {
            float4 xv = xp[j];
            float4 o;
            o.x = xv.x - r[j].x; o.y = xv.y - r[j].y;
            o.z = xv.z - r[j].z; o.w = xv.w - r[j].w;
            op[j] = o;
        }
    }
}

extern "C" void kernel_launch(void* const* d_in, const int* in_sizes, int n_in,
                              void* d_out, int out_size, void* d_ws, size_t ws_size,
                              hipStream_t stream) {
    const float* x = (const float*)d_in[0];
    const float* cb = (const float*)d_in[1];
    float* out = (float*)d_out;
    const int n_tokens = in_sizes[0] / D;          // 65536
    const int grid = (n_tokens + TPB - 1) / TPB;   // 256
    rvq_fp32_kernel<<<grid, TPB, 0, stream>>>(x, cb, out, n_tokens);
}

// Round 3
// 431.060 us; speedup vs baseline: 5.1023x; 5.1023x over previous
//
#include <hip/hip_runtime.h>

#define NQ 8
#define KCODES 1024
#define D 64
#define CHUNK 128
#define NCHUNK 8
#define TPB 256

using short8 = __attribute__((ext_vector_type(8))) short;
using f32x4  = __attribute__((ext_vector_type(4))) float;

static __device__ __forceinline__ unsigned bf16_rne_bits(float f) {
    unsigned u = __float_as_uint(f);
    return (u + 0x7fffu + ((u >> 16) & 1u)) >> 16;   // bf16 RNE bit pattern
}

// ---------------- prologue 1: split codebook into bf16 hi/lo granules ----------------
// ws_cb layout: [q][chunk][plane][code_in_chunk], plane = term*8 + kt*4 + g.
// granule = 8 bf16 covering dims kt*32 + g*8 .. +7 of one code (16B).
__global__ __launch_bounds__(256) void prep_cb(const float* __restrict__ cb,
                                               int4* __restrict__ ws_cb) {
    int id = blockIdx.x * 256 + threadIdx.x;       // 0 .. 131071
    int slot = id & 2047;
    int qc = id >> 11;
    int q = qc >> 3, ch = qc & 7;
    int plane = slot >> 7, n_rel = slot & 127;
    int g = plane & 3, kt = (plane >> 2) & 1, term = plane >> 3;
    int n = ch * CHUNK + n_rel;
    const float* src = cb + ((size_t)(q * KCODES + n)) * D + kt * 32 + g * 8;
    union { short s[8]; int4 v; } u;
    #pragma unroll
    for (int j = 0; j < 8; ++j) {
        float f = src[j];
        unsigned hb = bf16_rne_bits(f);
        if (term == 0) {
            u.s[j] = (short)hb;
        } else {
            float lo = f - __uint_as_float(hb << 16);
            u.s[j] = (short)bf16_rne_bits(lo);
        }
    }
    ws_cb[id] = u.v;
}

// ---------------- prologue 2: c_sq per (q, code), round-1-identical arithmetic ----------------
__global__ __launch_bounds__(256) void prep_csq(const float* __restrict__ cb,
                                                float* __restrict__ ws_csq) {
    int id = blockIdx.x * 256 + threadIdx.x;       // 0 .. 8191
    const float* c = cb + (size_t)id * D;
    float s0 = 0.f, s1 = 0.f, s2 = 0.f, s3 = 0.f;
    #pragma unroll
    for (int j = 0; j < 16; ++j) {
        s0 = fmaf(c[4*j+0], c[4*j+0], s0);
        s1 = fmaf(c[4*j+1], c[4*j+1], s1);
        s2 = fmaf(c[4*j+2], c[4*j+2], s2);
        s3 = fmaf(c[4*j+3], c[4*j+3], s3);
    }
    ws_csq[id] = (s0 + s1) + (s2 + s3);
}

// ---------------- main kernel ----------------
__global__ __launch_bounds__(TPB, 4) void rvq_mfma(
    const float* __restrict__ x,
    const float* __restrict__ cb,
    const int4* __restrict__ ws_cb,
    const float* __restrict__ ws_csq,
    float* __restrict__ out)
{
    // lds_cb (chunk staging) and lds_resid (refine exchange) alias; phases barrier-separated
    __shared__ __align__(16) char smem[32768];
    int4*  lds_cb    = (int4*)smem;
    float* lds_resid = (float*)smem;               // [64 tokens][68 floats]
    __shared__ float lds_csq[CHUNK];
    __shared__ int2  lds_cand[64];
    __shared__ int   lds_pick[64];

    const int tid  = threadIdx.x;
    const int lane = tid & 63;
    const int wave = tid >> 6;
    const int g    = lane >> 4;        // quad
    const int c    = lane & 15;
    const int tok  = blockIdx.x * 64 + wave * 16 + c;

    const float4* xp = (const float4*)(x + (size_t)tok * D);
    // lane holds dims [8g..8g+7] and [32+8g..32+8g+7] of token c (within wave)
    float4 rv0 = xp[g*2], rv1 = xp[g*2+1], rv2 = xp[8+g*2], rv3 = xp[8+g*2+1];

    for (int q = 0; q < NQ; ++q) {
        // ---- split residual into bf16 hi/lo A-fragments ----
        short8 ah0, al0, ah1, al1;
        {
            float f[16] = {rv0.x,rv0.y,rv0.z,rv0.w, rv1.x,rv1.y,rv1.z,rv1.w,
                           rv2.x,rv2.y,rv2.z,rv2.w, rv3.x,rv3.y,rv3.z,rv3.w};
            #pragma unroll
            for (int j = 0; j < 8; ++j) {
                unsigned hb = bf16_rne_bits(f[j]);
                float lo = f[j] - __uint_as_float(hb << 16);
                ah0[j] = (short)hb; al0[j] = (short)bf16_rne_bits(lo);
                unsigned hb1 = bf16_rne_bits(f[8+j]);
                float lo1 = f[8+j] - __uint_as_float(hb1 << 16);
                ah1[j] = (short)hb1; al1[j] = (short)bf16_rne_bits(lo1);
            }
        }

        float d1[4], d2[4]; int i1[4], i2[4];
        #pragma unroll
        for (int r = 0; r < 4; ++r) { d1[r] = 3.0e38f; d2[r] = 3.0e38f; i1[r] = 0; i2[r] = 0; }

        for (int ch = 0; ch < NCHUNK; ++ch) {
            __syncthreads();   // previous phase (compute/refine) fully done
            {
                const int4* src = ws_cb + (size_t)(q * NCHUNK + ch) * 2048;
                #pragma unroll
                for (int t = 0; t < 8; ++t) lds_cb[tid + t * 256] = src[tid + t * 256];
                if (tid < CHUNK) lds_csq[tid] = ws_csq[q * KCODES + ch * CHUNK + tid];
            }
            __syncthreads();

            const char* base = (const char*)lds_cb;
            #pragma unroll
            for (int tile = 0; tile < 8; ++tile) {
                const int nn = tile * 16 + c;
                short8 bh0 = *(const short8*)(base + (((0*8 + 0*4 + g) * 128) + nn) * 16);
                short8 bh1 = *(const short8*)(base + (((0*8 + 1*4 + g) * 128) + nn) * 16);
                short8 bl0 = *(const short8*)(base + (((1*8 + 0*4 + g) * 128) + nn) * 16);
                short8 bl1 = *(const short8*)(base + (((1*8 + 1*4 + g) * 128) + nn) * 16);
                f32x4 acc = {0.f, 0.f, 0.f, 0.f};
                acc = __builtin_amdgcn_mfma_f32_16x16x32_bf16(ah0, bh0, acc, 0, 0, 0);
                acc = __builtin_amdgcn_mfma_f32_16x16x32_bf16(ah1, bh1, acc, 0, 0, 0);
                acc = __builtin_amdgcn_mfma_f32_16x16x32_bf16(al0, bh0, acc, 0, 0, 0);
                acc = __builtin_amdgcn_mfma_f32_16x16x32_bf16(ah0, bl0, acc, 0, 0, 0);
                acc = __builtin_amdgcn_mfma_f32_16x16x32_bf16(al1, bh1, acc, 0, 0, 0);
                acc = __builtin_amdgcn_mfma_f32_16x16x32_bf16(ah1, bl1, acc, 0, 0, 0);
                acc = __builtin_amdgcn_mfma_f32_16x16x32_bf16(al0, bl0, acc, 0, 0, 0);
                acc = __builtin_amdgcn_mfma_f32_16x16x32_bf16(al1, bl1, acc, 0, 0, 0);

                const float cs = lds_csq[nn];
                const int code = ch * CHUNK + nn;
                #pragma unroll
                for (int r = 0; r < 4; ++r) {
                    float d = fmaf(acc[r], -2.0f, cs);
                    bool lt1 = d < d1[r];
                    bool lt2 = d < d2[r];
                    d2[r] = lt1 ? d1[r] : (lt2 ? d : d2[r]);
                    i2[r] = lt1 ? i1[r] : (lt2 ? code : i2[r]);
                    d1[r] = lt1 ? d : d1[r];
                    i1[r] = lt1 ? code : i1[r];
                }
            }
        }

        // ---- cross-lane top-2 merge over the 16 c-lanes (xor 1,2,4,8) ----
        #pragma unroll
        for (int s = 1; s <= 8; s <<= 1) {
            #pragma unroll
            for (int r = 0; r < 4; ++r) {
                float od1 = __shfl_xor(d1[r], s);
                int   oi1 = __shfl_xor(i1[r], s);
                float od2 = __shfl_xor(d2[r], s);
                int   oi2 = __shfl_xor(i2[r], s);
                bool keep = (d1[r] < od1) || (d1[r] == od1 && i1[r] < oi1);
                float w1 = keep ? d1[r] : od1;  int wi1 = keep ? i1[r] : oi1;
                float l1 = keep ? od1 : d1[r];  int li1 = keep ? oi1 : i1[r];
                bool bsec = (od2 < d2[r]) || (od2 == d2[r] && oi2 < i2[r]);
                float y  = bsec ? od2 : d2[r];  int yi = bsec ? oi2 : i2[r];
                bool xw  = (l1 < y) || (l1 == y && li1 < yi);
                d2[r] = xw ? l1 : y;  i2[r] = xw ? li1 : yi;
                d1[r] = w1; i1[r] = wi1;
            }
        }

        // ---- publish candidates + residual to LDS ----
        __syncthreads();                     // all waves done reading lds_cb
        if (c == 0) {
            #pragma unroll
            for (int r = 0; r < 4; ++r)
                lds_cand[wave * 16 + g * 4 + r] = make_int2(i1[r], i2[r]);
        }
        {
            float* rr = lds_resid + (size_t)(wave * 16 + c) * 68;
            *(float4*)(rr + 8*g)      = rv0;
            *(float4*)(rr + 8*g + 4)  = rv1;
            *(float4*)(rr + 32 + 8*g) = rv2;
            *(float4*)(rr + 36 + 8*g) = rv3;
        }
        __syncthreads();

        // ---- ALWAYS-ON exact refinement, round-1-identical arithmetic ----
        // lanes 0..31: t = lane>>1 (token), lane&1 selects candidate
        {
            const int t = (lane >> 1) & 15;
            const int2 cnd = lds_cand[wave * 16 + t];
            const int cd = (lane & 1) ? cnd.y : cnd.x;
            const float4* rrv = (const float4*)(lds_resid + (size_t)(wave * 16 + t) * 68);
            const float4* cpv = (const float4*)(cb + ((size_t)(q * KCODES + cd)) * D);
            float ax = 0.f, ay = 0.f, az = 0.f, aw = 0.f;
            #pragma unroll
            for (int j = 0; j < 16; ++j) {
                float4 rv = rrv[j];
                float4 cv = cpv[j];
                ax = fmaf(rv.x, cv.x, ax);
                ay = fmaf(rv.y, cv.y, ay);
                az = fmaf(rv.z, cv.z, az);
                aw = fmaf(rv.w, cv.w, aw);
            }
            float dot = (ax + ay) + (az + aw);
            float dd = fmaf(dot, -2.0f, ws_csq[q * KCODES + cd]);
            float od = __shfl_xor(dd, 1);
            // reconstruct (d(bi1), d(bi2)) on every lane of the pair
            float dA = (lane & 1) ? od : dd;   // d(cnd.x)
            float dB = (lane & 1) ? dd : od;   // d(cnd.y)
            int lo  = cnd.x < cnd.y ? cnd.x : cnd.y;
            int hi  = cnd.x < cnd.y ? cnd.y : cnd.x;
            float dlo = cnd.x < cnd.y ? dA : dB;
            float dhi = cnd.x < cnd.y ? dB : dA;
            int pick = (dhi < dlo) ? hi : lo;  // strict-<, lower index wins ties
            if (lane < 32 && (lane & 1) == 0) lds_pick[wave * 16 + t] = pick;
        }
        __syncthreads();
        const int ifin = lds_pick[wave * 16 + c];

        // ---- residual update: r -= cb[q][ifin] (this lane's 16 dims) ----
        {
            const float4* cp = (const float4*)(cb + ((size_t)(q * KCODES + ifin)) * D);
            float4 c0 = cp[g*2], c1 = cp[g*2+1], c2 = cp[8+g*2], c3 = cp[8+g*2+1];
            rv0.x -= c0.x; rv0.y -= c0.y; rv0.z -= c0.z; rv0.w -= c0.w;
            rv1.x -= c1.x; rv1.y -= c1.y; rv1.z -= c1.z; rv1.w -= c1.w;
            rv2.x -= c2.x; rv2.y -= c2.y; rv2.z -= c2.z; rv2.w -= c2.w;
            rv3.x -= c3.x; rv3.y -= c3.y; rv3.z -= c3.z; rv3.w -= c3.w;
        }
    }

    // ---- epilogue: out = x - residual_final ----
    {
        float4* op = (float4*)(out + (size_t)tok * D);
        float4 xv0 = xp[g*2], xv1 = xp[g*2+1], xv2 = xp[8+g*2], xv3 = xp[8+g*2+1];
        float4 o0, o1, o2, o3;
        o0.x = xv0.x - rv0.x; o0.y = xv0.y - rv0.y; o0.z = xv0.z - rv0.z; o0.w = xv0.w - rv0.w;
        o1.x = xv1.x - rv1.x; o1.y = xv1.y - rv1.y; o1.z = xv1.z - rv1.z; o1.w = xv1.w - rv1.w;
        o2.x = xv2.x - rv2.x; o2.y = xv2.y - rv2.y; o2.z = xv2.z - rv2.z; o2.w = xv2.w - rv2.w;
        o3.x = xv3.x - rv3.x; o3.y = xv3.y - rv3.y; o3.z = xv3.z - rv3.z; o3.w = xv3.w - rv3.w;
        op[g*2] = o0; op[g*2+1] = o1; op[8+g*2] = o2; op[8+g*2+1] = o3;
    }
}

extern "C" void kernel_launch(void* const* d_in, const int* in_sizes, int n_in,
                              void* d_out, int out_size, void* d_ws, size_t ws_size,
                              hipStream_t stream) {
    const float* x  = (const float*)d_in[0];
    const float* cb = (const float*)d_in[1];
    float* out = (float*)d_out;

    int4*  ws_cb  = (int4*)d_ws;                                     // 2 MB
    float* ws_csq = (float*)((char*)d_ws + (size_t)2 * 1024 * 1024); // 32 KB

    prep_cb <<<512, 256, 0, stream>>>(cb, ws_cb);
    prep_csq<<< 32, 256, 0, stream>>>(cb, ws_csq);

    const int n_tokens = in_sizes[0] / D;            // 65536
    const int grid = n_tokens / 64;                  // 1024 blocks
    rvq_mfma<<<grid, TPB, 0, stream>>>(x, cb, ws_cb, ws_csq, out);
}

// Round 4
// 421.336 us; speedup vs baseline: 5.2200x; 1.0231x over previous
//
#include <hip/hip_runtime.h>

#define NQ 8
#define KCODES 1024
#define D 64
#define CHUNK 128
#define NCHUNK 8
#define TPB 512
#define TOKPB 128            // tokens per block

using short8 = __attribute__((ext_vector_type(8))) short;
using f32x4  = __attribute__((ext_vector_type(4))) float;

static __device__ __forceinline__ unsigned bf16_rne_bits(float f) {
    unsigned u = __float_as_uint(f);
    return (u + 0x7fffu + ((u >> 16) & 1u)) >> 16;   // bf16 RNE bit pattern
}

// ---------------- prologue 1: split codebook into bf16 hi/lo granules ----------------
// ws_cb layout: [q][chunk][plane][code_in_chunk], plane = term*8 + kt*4 + g.
__global__ __launch_bounds__(256) void prep_cb(const float* __restrict__ cb,
                                               int4* __restrict__ ws_cb) {
    int id = blockIdx.x * 256 + threadIdx.x;       // 0 .. 131071
    int slot = id & 2047;
    int qc = id >> 11;
    int q = qc >> 3, ch = qc & 7;
    int plane = slot >> 7, n_rel = slot & 127;
    int g = plane & 3, kt = (plane >> 2) & 1, term = plane >> 3;
    int n = ch * CHUNK + n_rel;
    const float* src = cb + ((size_t)(q * KCODES + n)) * D + kt * 32 + g * 8;
    union { short s[8]; int4 v; } u;
    #pragma unroll
    for (int j = 0; j < 8; ++j) {
        float f = src[j];
        unsigned hb = bf16_rne_bits(f);
        if (term == 0) {
            u.s[j] = (short)hb;
        } else {
            float lo = f - __uint_as_float(hb << 16);
            u.s[j] = (short)bf16_rne_bits(lo);
        }
    }
    ws_cb[id] = u.v;
}

// ---------------- prologue 2: c_sq (exact, round-3 arithmetic) + seed (-csq/2) ----------------
__global__ __launch_bounds__(256) void prep_csq(const float* __restrict__ cb,
                                                float* __restrict__ ws_csq,
                                                float* __restrict__ ws_csqh) {
    int id = blockIdx.x * 256 + threadIdx.x;       // 0 .. 8191
    const float* c = cb + (size_t)id * D;
    float s0 = 0.f, s1 = 0.f, s2 = 0.f, s3 = 0.f;
    #pragma unroll
    for (int j = 0; j < 16; ++j) {
        s0 = fmaf(c[4*j+0], c[4*j+0], s0);
        s1 = fmaf(c[4*j+1], c[4*j+1], s1);
        s2 = fmaf(c[4*j+2], c[4*j+2], s2);
        s3 = fmaf(c[4*j+3], c[4*j+3], s3);
    }
    float cs = (s0 + s1) + (s2 + s3);
    ws_csq[id]  = cs;            // exact, used by refine (bit-identical to round 3)
    ws_csqh[id] = -0.5f * cs;    // MFMA accumulator seed (exact scaling)
}

// ---------------- main kernel ----------------
__global__ __launch_bounds__(TPB, 4) void rvq_mfma(
    const float* __restrict__ x,
    const float* __restrict__ cb,
    const int4* __restrict__ ws_cb,
    const float* __restrict__ ws_csq,
    const float* __restrict__ ws_csqh,
    float* __restrict__ out)
{
    // chunk staging (32768 B) aliases refine residual buffer (128*68*4 = 34816 B)
    __shared__ __align__(16) char smem[TOKPB * 68 * 4];
    int4*  lds_cb    = (int4*)smem;
    float* lds_resid = (float*)smem;
    __shared__ float lds_csqh[CHUNK];
    __shared__ int2  lds_cand[TOKPB];
    __shared__ int   lds_pick[TOKPB];

    const int tid  = threadIdx.x;
    const int lane = tid & 63;
    const int wave = tid >> 6;          // 0..7
    const int g    = lane >> 4;         // quad
    const int c    = lane & 15;
    const int ltok = wave * 16 + c;     // token within block
    const int tok  = blockIdx.x * TOKPB + ltok;

    const float4* xp = (const float4*)(x + (size_t)tok * D);
    // lane holds dims [8g..8g+7] and [32+8g..32+8g+7] of its wave-token c
    float4 rv0 = xp[g*2], rv1 = xp[g*2+1], rv2 = xp[8+g*2], rv3 = xp[8+g*2+1];

    // static LDS base for B-fragment reads: all 32 reads use compile-time offsets
    const char* bp = smem + (c << 4) + (g << 11);

    for (int q = 0; q < NQ; ++q) {
        // ---- split residual into bf16 hi/lo A-fragments (no local array) ----
        short8 ah0, al0, ah1, al1;
        {
            const float* fv0 = (const float*)&rv0;
            const float* fv1 = (const float*)&rv1;
            const float* fv2 = (const float*)&rv2;
            const float* fv3 = (const float*)&rv3;
            #pragma unroll
            for (int j = 0; j < 4; ++j) {
                float a = fv0[j], b = fv1[j], e = fv2[j], f = fv3[j];
                unsigned ha = bf16_rne_bits(a);
                unsigned hbv = bf16_rne_bits(b);
                unsigned he = bf16_rne_bits(e);
                unsigned hf = bf16_rne_bits(f);
                ah0[j]   = (short)ha;  ah0[4+j] = (short)hbv;
                ah1[j]   = (short)he;  ah1[4+j] = (short)hf;
                al0[j]   = (short)bf16_rne_bits(a - __uint_as_float(ha  << 16));
                al0[4+j] = (short)bf16_rne_bits(b - __uint_as_float(hbv << 16));
                al1[j]   = (short)bf16_rne_bits(e - __uint_as_float(he  << 16));
                al1[4+j] = (short)bf16_rne_bits(f - __uint_as_float(hf  << 16));
            }
        }

        // argmax tracking of v = dot - csq/2  (ranking-equivalent to argmin dist)
        float d1[4], d2[4]; int i1[4], i2[4];
        #pragma unroll
        for (int r = 0; r < 4; ++r) { d1[r] = -3.0e38f; d2[r] = -3.0e38f; i1[r] = 0; i2[r] = 0; }

        for (int ch = 0; ch < NCHUNK; ++ch) {
            __syncthreads();   // previous phase fully done before overwriting smem
            {
                const int4* src = ws_cb + (size_t)(q * NCHUNK + ch) * 2048;
                #pragma unroll
                for (int t = 0; t < 4; ++t) lds_cb[tid + t * TPB] = src[tid + t * TPB];
                if (tid < CHUNK) lds_csqh[tid] = ws_csqh[q * KCODES + ch * CHUNK + tid];
            }
            __syncthreads();

            const int code_base = ch * CHUNK + c;
            #pragma unroll
            for (int tile = 0; tile < 8; ++tile) {
                // compile-time ds_read offsets: plane {g, 4+g, 8+g, 12+g} x tile
                short8 bh0 = *(const short8*)(bp + tile * 256);
                short8 bh1 = *(const short8*)(bp + 8192  + tile * 256);
                short8 bl0 = *(const short8*)(bp + 16384 + tile * 256);
                short8 bl1 = *(const short8*)(bp + 24576 + tile * 256);
                const float sd = lds_csqh[tile * 16 + c];
                f32x4 acc = {sd, sd, sd, sd};
                acc = __builtin_amdgcn_mfma_f32_16x16x32_bf16(ah0, bh0, acc, 0, 0, 0);
                acc = __builtin_amdgcn_mfma_f32_16x16x32_bf16(ah1, bh1, acc, 0, 0, 0);
                acc = __builtin_amdgcn_mfma_f32_16x16x32_bf16(al0, bh0, acc, 0, 0, 0);
                acc = __builtin_amdgcn_mfma_f32_16x16x32_bf16(ah0, bl0, acc, 0, 0, 0);
                acc = __builtin_amdgcn_mfma_f32_16x16x32_bf16(al1, bh1, acc, 0, 0, 0);
                acc = __builtin_amdgcn_mfma_f32_16x16x32_bf16(ah1, bl1, acc, 0, 0, 0);
                acc = __builtin_amdgcn_mfma_f32_16x16x32_bf16(al0, bl0, acc, 0, 0, 0);
                acc = __builtin_amdgcn_mfma_f32_16x16x32_bf16(al1, bl1, acc, 0, 0, 0);

                const int codev = code_base + tile * 16;
                #pragma unroll
                for (int r = 0; r < 4; ++r) {
                    float v = acc[r];
                    bool gt1 = v > d1[r];
                    bool gt2 = v > d2[r];
                    float vm = fminf(v, d1[r]);
                    d1[r] = fmaxf(v, d1[r]);
                    d2[r] = gt2 ? vm : d2[r];
                    i2[r] = gt1 ? i1[r] : (gt2 ? codev : i2[r]);
                    i1[r] = gt1 ? codev : i1[r];
                }
            }
        }

        // ---- cross-lane top-2 (max-form) merge over the 16 c-lanes ----
        #pragma unroll
        for (int s = 1; s <= 8; s <<= 1) {
            #pragma unroll
            for (int r = 0; r < 4; ++r) {
                float od1 = __shfl_xor(d1[r], s);
                int   oi1 = __shfl_xor(i1[r], s);
                float od2 = __shfl_xor(d2[r], s);
                int   oi2 = __shfl_xor(i2[r], s);
                bool keep = (d1[r] > od1) || (d1[r] == od1 && i1[r] < oi1);
                float w1 = keep ? d1[r] : od1;  int wi1 = keep ? i1[r] : oi1;
                float l1 = keep ? od1 : d1[r];  int li1 = keep ? oi1 : i1[r];
                bool bsec = (od2 > d2[r]) || (od2 == d2[r] && oi2 < i2[r]);
                float y  = bsec ? od2 : d2[r];  int yi = bsec ? oi2 : i2[r];
                bool xw  = (l1 > y) || (l1 == y && li1 < yi);
                d2[r] = xw ? l1 : y;  i2[r] = xw ? li1 : yi;
                d1[r] = w1; i1[r] = wi1;
            }
        }

        // ---- publish candidates + residual to LDS ----
        __syncthreads();                     // all waves done reading lds_cb
        if (c == 0) {
            #pragma unroll
            for (int r = 0; r < 4; ++r)
                lds_cand[wave * 16 + g * 4 + r] = make_int2(i1[r], i2[r]);
        }
        {
            float* rr = lds_resid + (size_t)ltok * 68;
            *(float4*)(rr + 8*g)      = rv0;
            *(float4*)(rr + 8*g + 4)  = rv1;
            *(float4*)(rr + 32 + 8*g) = rv2;
            *(float4*)(rr + 36 + 8*g) = rv3;
        }
        __syncthreads();

        // ---- ALWAYS-ON exact refinement, bit-identical to round 3 ----
        {
            const int t = (lane >> 1) & 15;
            const int2 cnd = lds_cand[wave * 16 + t];
            const int cd = (lane & 1) ? cnd.y : cnd.x;
            const float4* rrv = (const float4*)(lds_resid + (size_t)(wave * 16 + t) * 68);
            const float4* cpv = (const float4*)(cb + ((size_t)(q * KCODES + cd)) * D);
            float ax = 0.f, ay = 0.f, az = 0.f, aw = 0.f;
            #pragma unroll
            for (int j = 0; j < 16; ++j) {
                float4 rv = rrv[j];
                float4 cv = cpv[j];
                ax = fmaf(rv.x, cv.x, ax);
                ay = fmaf(rv.y, cv.y, ay);
                az = fmaf(rv.z, cv.z, az);
                aw = fmaf(rv.w, cv.w, aw);
            }
            float dot = (ax + ay) + (az + aw);
            float dd = fmaf(dot, -2.0f, ws_csq[q * KCODES + cd]);
            float od = __shfl_xor(dd, 1);
            float dA = (lane & 1) ? od : dd;   // d(cnd.x)
            float dB = (lane & 1) ? dd : od;   // d(cnd.y)
            int lo  = cnd.x < cnd.y ? cnd.x : cnd.y;
            int hi  = cnd.x < cnd.y ? cnd.y : cnd.x;
            float dlo = cnd.x < cnd.y ? dA : dB;
            float dhi = cnd.x < cnd.y ? dB : dA;
            int pick = (dhi < dlo) ? hi : lo;  // strict-<, lower index wins ties
            if (lane < 32 && (lane & 1) == 0) lds_pick[wave * 16 + t] = pick;
        }
        __syncthreads();
        const int ifin = lds_pick[ltok];

        // ---- residual update: r -= cb[q][ifin] (this lane's 16 dims) ----
        {
            const float4* cp = (const float4*)(cb + ((size_t)(q * KCODES + ifin)) * D);
            float4 c0 = cp[g*2], c1 = cp[g*2+1], c2 = cp[8+g*2], c3 = cp[8+g*2+1];
            rv0.x -= c0.x; rv0.y -= c0.y; rv0.z -= c0.z; rv0.w -= c0.w;
            rv1.x -= c1.x; rv1.y -= c1.y; rv1.z -= c1.z; rv1.w -= c1.w;
            rv2.x -= c2.x; rv2.y -= c2.y; rv2.z -= c2.z; rv2.w -= c2.w;
            rv3.x -= c3.x; rv3.y -= c3.y; rv3.z -= c3.z; rv3.w -= c3.w;
        }
    }

    // ---- epilogue: out = x - residual_final ----
    {
        float4* op = (float4*)(out + (size_t)tok * D);
        float4 xv0 = xp[g*2], xv1 = xp[g*2+1], xv2 = xp[8+g*2], xv3 = xp[8+g*2+1];
        float4 o0, o1, o2, o3;
        o0.x = xv0.x - rv0.x; o0.y = xv0.y - rv0.y; o0.z = xv0.z - rv0.z; o0.w = xv0.w - rv0.w;
        o1.x = xv1.x - rv1.x; o1.y = xv1.y - rv1.y; o1.z = xv1.z - rv1.z; o1.w = xv1.w - rv1.w;
        o2.x = xv2.x - rv2.x; o2.y = xv2.y - rv2.y; o2.z = xv2.z - rv2.z; o2.w = xv2.w - rv2.w;
        o3.x = xv3.x - rv3.x; o3.y = xv3.y - rv3.y; o3.z = xv3.z - rv3.z; o3.w = xv3.w - rv3.w;
        op[g*2] = o0; op[g*2+1] = o1; op[8+g*2] = o2; op[8+g*2+1] = o3;
    }
}

extern "C" void kernel_launch(void* const* d_in, const int* in_sizes, int n_in,
                              void* d_out, int out_size, void* d_ws, size_t ws_size,
                              hipStream_t stream) {
    const float* x  = (const float*)d_in[0];
    const float* cb = (const float*)d_in[1];
    float* out = (float*)d_out;

    int4*  ws_cb   = (int4*)d_ws;                                      // 2 MB
    float* ws_csq  = (float*)((char*)d_ws + (size_t)2 * 1024 * 1024);  // 32 KB
    float* ws_csqh = ws_csq + 8192;                                    // 32 KB

    prep_cb <<<512, 256, 0, stream>>>(cb, ws_cb);
    prep_csq<<< 32, 256, 0, stream>>>(cb, ws_csq, ws_csqh);

    const int n_tokens = in_sizes[0] / D;            // 65536
    const int grid = n_tokens / TOKPB;               // 512 blocks
    rvq_mfma<<<grid, TPB, 0, stream>>>(x, cb, ws_cb, ws_csq, ws_csqh, out);
}